// Round 8
// baseline (6466.573 us; speedup 1.0000x reference)
//
#include <hip/hip_runtime.h>
#include <cstdint>
#include <cstddef>

#define Hn 256
#define Sn 2048
#define Bn 128
#define NT 1024

typedef _Float16 half2_t __attribute__((ext_vector_type(2)));

__device__ __forceinline__ half2_t bc2_(unsigned int u){ return __builtin_bit_cast(half2_t, u); }

__device__ __forceinline__ float fdot2_(half2_t a, half2_t b, float c){
#if __has_builtin(__builtin_amdgcn_fdot2)
  return __builtin_amdgcn_fdot2(a, b, c, false);
#else
  float d;
  asm volatile("v_dot2_f32_f16 %0, %1, %2, %3" : "=v"(d) : "v"(a), "v"(b), "v"(c));
  return d;
#endif
}

__device__ __forceinline__ float rfl_(float v){
  return __builtin_bit_cast(float, __builtin_amdgcn_readfirstlane(__builtin_bit_cast(int, v)));
}

__device__ __forceinline__ half2_t pkrtz_(float a, float b){
  return __builtin_bit_cast(half2_t, __builtin_amdgcn_cvt_pkrtz(a, b));
}

// quad (4-lane) sum via DPP quad_perm — pure VALU
__device__ __forceinline__ float qsum_(float v){
  int x = __builtin_bit_cast(int, v);
  int y = __builtin_amdgcn_mov_dpp(x, 0xB1, 0xF, 0xF, true);
  v += __builtin_bit_cast(float, y);
  x = __builtin_bit_cast(int, v);
  y = __builtin_amdgcn_mov_dpp(x, 0x4E, 0xF, 0xF, true);
  return v + __builtin_bit_cast(float, y);
}

// wave(64) sum via DPP row_shr/row_bcast — result valid in lane 63 of the wave
__device__ __forceinline__ float wsum_(float v){
  int x;
  x = __builtin_amdgcn_update_dpp(0, __builtin_bit_cast(int, v), 0x111, 0xF, 0xF, false);
  v += __builtin_bit_cast(float, x);   // row_shr:1
  x = __builtin_amdgcn_update_dpp(0, __builtin_bit_cast(int, v), 0x112, 0xF, 0xF, false);
  v += __builtin_bit_cast(float, x);   // row_shr:2
  x = __builtin_amdgcn_update_dpp(0, __builtin_bit_cast(int, v), 0x114, 0xF, 0xF, false);
  v += __builtin_bit_cast(float, x);   // row_shr:4
  x = __builtin_amdgcn_update_dpp(0, __builtin_bit_cast(int, v), 0x118, 0xF, 0xF, false);
  v += __builtin_bit_cast(float, x);   // row_shr:8 -> lane15 of each row = row sum
  x = __builtin_amdgcn_update_dpp(0, __builtin_bit_cast(int, v), 0x142, 0xA, 0xF, false);
  v += __builtin_bit_cast(float, x);   // row_bcast:15 into rows 1,3
  x = __builtin_amdgcn_update_dpp(0, __builtin_bit_cast(int, v), 0x143, 0xC, 0xF, false);
  v += __builtin_bit_cast(float, x);   // row_bcast:31 into rows 2,3 -> lane63 total
  return v;
}

__device__ __forceinline__ float sigmoid_(float v){ return 1.0f/(1.0f+__expf(-v)); }
__device__ __forceinline__ float tanh_(float v){
  float e = __expf(-2.0f*__builtin_fabsf(v));
  float r = (1.0f-e)/(1.0f+e);
  return __builtin_copysignf(r, v);
}

#define F32_(M) M(0) M(1) M(2) M(3) M(4) M(5) M(6) M(7) M(8) M(9) M(10) M(11) \
  M(12) M(13) M(14) M(15) M(16) M(17) M(18) M(19) M(20) M(21) M(22) M(23) \
  M(24) M(25) M(26) M(27) M(28) M(29) M(30) M(31)

// 1024 thr/block, 1 block/CU (LDS ~100 KB forces it -> 16 waves = 4/SIMD ->
// unified reg budget 128/thread). Thread t: j=t>>2, kq=t&3. Rows {j,j+256,
// j+512}, K-quarter [64kq,64kq+64). Weights: r,z rows in 64 AGPRs (the RA caps
// arch-VGPRs at 64 -- rounds 1-7 -- but AGPRs are a separate 64-slot pool);
// n-row: 16 dwords VGPR + 16 dwords LDS. No per-step global weight traffic.
__global__ void __launch_bounds__(NT)
bio_rnn(const float* __restrict__ x,
        const float* __restrict__ w_ih, const float* __restrict__ w_hh,
        const float* __restrict__ b_ih, const float* __restrict__ b_hh,
        const float* __restrict__ w_gain, const float* __restrict__ b_gain,
        const float* __restrict__ w_bias, const float* __restrict__ b_bias,
        const float* __restrict__ w_reflex, const float* __restrict__ b_reflex,
        const float* __restrict__ w_policy, const float* __restrict__ b_policy,
        const float* __restrict__ w_motor, const float* __restrict__ b_motor,
        float* __restrict__ y_out, float* __restrict__ router)
{
  const int b  = blockIdx.x;
  const int t  = threadIdx.x;
  const int kq = t & 3;
  const int j  = t >> 2;

  __shared__ unsigned int WL[NT * 20];          // n-row cols[32:64) f16, 80 B stride
  __shared__ __align__(16) unsigned char hraw[4*160];  // h f16, 4 chunks of 64
  __shared__ float PRE[4][Hn];
  __shared__ float REDp[4][8];
  __shared__ float REDq[4][4];
  __shared__ float HW[13][Hn];
  __shared__ float SB[10];

  // ---- AGPR weights: r,z rows, 32 dwords each ----
#define DAG(i) unsigned agr##i, agz##i;
  F32_(DAG)
#undef DAG
  {
    const float* wrR = w_hh + (size_t)(j      )*Hn + kq*64;
    const float* wrZ = w_hh + (size_t)(j + Hn )*Hn + kq*64;
#define WAG(i) { unsigned pr = __builtin_bit_cast(unsigned, pkrtz_(wrR[2*i], wrR[2*i+1])); \
                 unsigned pz = __builtin_bit_cast(unsigned, pkrtz_(wrZ[2*i], wrZ[2*i+1])); \
                 asm("v_accvgpr_write_b32 %0, %1" : "=a"(agr##i) : "v"(pr)); \
                 asm("v_accvgpr_write_b32 %0, %1" : "=a"(agz##i) : "v"(pz)); }
    F32_(WAG)
#undef WAG
  }
  // ---- n-row: cols[0:32) in VGPRs, cols[32:64) in LDS ----
  uint4 WR0, WR1, WR2, WR3;
  {
    const float* wrN = w_hh + (size_t)(j + 2*Hn)*Hn + kq*64;
#define PK(m) __builtin_bit_cast(unsigned, pkrtz_(wrN[2*(m)], wrN[2*(m)+1]))
    WR0 = (uint4){PK(0),PK(1),PK(2),PK(3)};
    WR1 = (uint4){PK(4),PK(5),PK(6),PK(7)};
    WR2 = (uint4){PK(8),PK(9),PK(10),PK(11)};
    WR3 = (uint4){PK(12),PK(13),PK(14),PK(15)};
    #pragma unroll
    for (int i = 0; i < 16; i++)
      WL[t*20 + i] = __builtin_bit_cast(unsigned, pkrtz_(wrN[32+2*i], wrN[32+2*i+1]));
#undef PK
  }
  // gi fold: kq 0/1/2 carry x-dims {2kq,2kq+1}; kq==3 carries the biases.
  half2_t wi0, wi1, wi2; float bd0, bd1, bd2, bd3;
  {
    half2_t z; z.x=(_Float16)0.f; z.y=(_Float16)0.f;
    wi0=z; wi1=z; wi2=z; bd0=bd1=bd2=bd3=0.f;
    if (kq < 3){
      wi0 = pkrtz_(w_ih[(size_t)(j       )*6+2*kq], w_ih[(size_t)(j       )*6+2*kq+1]);
      wi1 = pkrtz_(w_ih[(size_t)(j +  Hn )*6+2*kq], w_ih[(size_t)(j +  Hn )*6+2*kq+1]);
      wi2 = pkrtz_(w_ih[(size_t)(j + 2*Hn)*6+2*kq], w_ih[(size_t)(j + 2*Hn)*6+2*kq+1]);
    } else {
      bd0 = b_ih[j]      + b_hh[j];
      bd1 = b_ih[j+Hn]   + b_hh[j+Hn];
      bd2 = b_hh[j+2*Hn];                 // gh_n bias
      bd3 = b_ih[j+2*Hn];                 // gi_n bias
    }
  }
  if (t < Hn){
    HW[0][t] = w_gain[t];        HW[1][t]  = w_gain[Hn + t];
    HW[2][t] = w_bias[t];        HW[3][t]  = w_bias[Hn + t];
    HW[4][t] = w_bias[2*Hn + t]; HW[5][t]  = w_bias[3*Hn + t];
    HW[6][t] = w_reflex[2*t];    HW[7][t]  = w_reflex[2*t + 1];
    HW[8][t] = b_reflex[t];
    HW[9][t] = w_policy[t];      HW[10][t] = w_policy[Hn + t];
    HW[11][t] = w_motor[t];      HW[12][t] = w_motor[Hn + t];
  }
  if (t < 160) ((unsigned int*)hraw)[t] = 0u;
  if (t == 0){
    SB[0]=b_gain[0]; SB[1]=b_gain[1];
    SB[2]=b_bias[0]; SB[3]=b_bias[1]; SB[4]=b_bias[2]; SB[5]=b_bias[3];
    SB[6]=b_policy[0]; SB[7]=b_policy[1]; SB[8]=b_motor[0]; SB[9]=b_motor[1];
  }
  float hprev = 0.f;
  __syncthreads();

  const float* xp   = x      + (size_t)b * Sn * 6;
  float* rbase      = router + (size_t)b * Sn * Hn;
  const uint4* hc4  = (const uint4*)(hraw + kq*160);   // this quarter's h (8 uint4)
  const uint4* WLv  = (const uint4*)WL;                // row base t*5

  // chunk c: h uint4 hc4[c]; r/z from AGPR dwords 4c..4c+3; n from nv
#define GCH(c, nv_, r0,r1,r2,r3) { \
    const uint4 Hc = hc4[c]; const uint4 Nw = (nv_); \
    unsigned u0,u1,u2,u3,v0,v1,v2,v3; \
    asm("v_accvgpr_read_b32 %0, %1" : "=v"(u0) : "a"(agr##r0)); \
    asm("v_accvgpr_read_b32 %0, %1" : "=v"(u1) : "a"(agr##r1)); \
    asm("v_accvgpr_read_b32 %0, %1" : "=v"(u2) : "a"(agr##r2)); \
    asm("v_accvgpr_read_b32 %0, %1" : "=v"(u3) : "a"(agr##r3)); \
    asm("v_accvgpr_read_b32 %0, %1" : "=v"(v0) : "a"(agz##r0)); \
    asm("v_accvgpr_read_b32 %0, %1" : "=v"(v1) : "a"(agz##r1)); \
    asm("v_accvgpr_read_b32 %0, %1" : "=v"(v2) : "a"(agz##r2)); \
    asm("v_accvgpr_read_b32 %0, %1" : "=v"(v3) : "a"(agz##r3)); \
    a0=fdot2_(bc2_(u0),bc2_(Hc.x),a0); a1=fdot2_(bc2_(v0),bc2_(Hc.x),a1); a2=fdot2_(bc2_(Nw.x),bc2_(Hc.x),a2); \
    a0=fdot2_(bc2_(u1),bc2_(Hc.y),a0); a1=fdot2_(bc2_(v1),bc2_(Hc.y),a1); a2=fdot2_(bc2_(Nw.y),bc2_(Hc.y),a2); \
    a0=fdot2_(bc2_(u2),bc2_(Hc.z),a0); a1=fdot2_(bc2_(v2),bc2_(Hc.z),a1); a2=fdot2_(bc2_(Nw.z),bc2_(Hc.z),a2); \
    a0=fdot2_(bc2_(u3),bc2_(Hc.w),a0); a1=fdot2_(bc2_(v3),bc2_(Hc.w),a1); a2=fdot2_(bc2_(Nw.w),bc2_(Hc.w),a2); }

  for (int s = 0; s < Sn; s++){
    const float x0=rfl_(xp[0]), x1=rfl_(xp[1]), x2=rfl_(xp[2]);
    const float x3=rfl_(xp[3]), x4=rfl_(xp[4]), x5=rfl_(xp[5]);
    float xa = (kq==0)?x0:((kq==1)?x2:x4);
    float xb = (kq==0)?x1:((kq==1)?x3:x5);
    half2_t xpk = pkrtz_(xa, xb);

    float a0 = fdot2_(wi0, xpk, bd0);   // r row: gi fold
    float a1 = fdot2_(wi1, xpk, bd1);   // z row: gi fold
    float a2 = bd2;                     // gh_n
    float a3 = fdot2_(wi2, xpk, bd3);   // gi_n (kept separate)

    const int wlb = t*5;
    GCH(0, WR0,  0, 1, 2, 3)
    GCH(1, WR1,  4, 5, 6, 7)
    GCH(2, WR2,  8, 9,10,11)
    GCH(3, WR3, 12,13,14,15)
    GCH(4, WLv[wlb+0], 16,17,18,19)
    GCH(5, WLv[wlb+1], 20,21,22,23)
    GCH(6, WLv[wlb+2], 24,25,26,27)
    GCH(7, WLv[wlb+3], 28,29,30,31)

    a0 = qsum_(a0); a1 = qsum_(a1); a2 = qsum_(a2); a3 = qsum_(a3);
    if (kq == 0){ PRE[0][j]=a0; PRE[1][j]=a1; PRE[2][j]=a2; PRE[3][j]=a3; }
    __syncthreads();                                        // W1

    if (t < Hn){
      float pr = PRE[0][t], pz = PRE[1][t], pg = PRE[2][t], pn = PRE[3][t];
      float r = sigmoid_(pr);
      float z = sigmoid_(pz);
      float n = tanh_(pn + r*pg);
      float h = (1.f - z)*n + z*hprev;
      hprev = h;
      *(_Float16*)(hraw + (t>>6)*160 + (t&63)*2) = (_Float16)h;
      rbase[(size_t)s*Hn + t] = h;
      float p0 = wsum_(h*HW[0][t]);
      float p1 = wsum_(h*HW[1][t]);
      float p2 = wsum_(h*HW[2][t]);
      float p3 = wsum_(h*HW[3][t]);
      float p4 = wsum_(h*HW[4][t]);
      float p5 = wsum_(h*HW[5][t]);
      if ((t & 63) == 63){
        const int wv = t >> 6;
        REDp[wv][0]=p0; REDp[wv][1]=p1; REDp[wv][2]=p2;
        REDp[wv][3]=p3; REDp[wv][4]=p4; REDp[wv][5]=p5;
      }
    }
    __syncthreads();                                        // W2
    if (t < Hn){
      float g0 = REDp[0][0]+REDp[1][0]+REDp[2][0]+REDp[3][0] + SB[0];
      float g1 = REDp[0][1]+REDp[1][1]+REDp[2][1]+REDp[3][1] + SB[1];
      g0 = sigmoid_(g0); g1 = sigmoid_(g1);
      float f = (x0*g0)*HW[6][t] + (x1*g1)*HW[7][t] + HW[8][t];
      f = fmaxf(f, 0.f);                                    // feat
      float q0 = wsum_(f*HW[9][t]);
      float q1 = wsum_(f*HW[10][t]);
      float q2 = wsum_(f*HW[11][t]);
      float q3 = wsum_(f*HW[12][t]);
      if ((t & 63) == 63){
        const int wv = t >> 6;
        REDq[wv][0]=q0; REDq[wv][1]=q1; REDq[wv][2]=q2; REDq[wv][3]=q3;
      }
    }
    __syncthreads();                                        // W3
    if (t == 0){
      float s0 = REDq[0][0]+REDq[1][0]+REDq[2][0]+REDq[3][0];
      float s1 = REDq[0][1]+REDq[1][1]+REDq[2][1]+REDq[3][1];
      float s2 = REDq[0][2]+REDq[1][2]+REDq[2][2]+REDq[3][2];
      float s3 = REDq[0][3]+REDq[1][3]+REDq[2][3]+REDq[3][3];
      float B0 = REDp[0][2]+REDp[1][2]+REDp[2][2]+REDp[3][2] + SB[2];
      float B1 = REDp[0][3]+REDp[1][3]+REDp[2][3]+REDp[3][3] + SB[3];
      float B2 = REDp[0][4]+REDp[1][4]+REDp[2][4]+REDp[3][4] + SB[4];
      float B3 = REDp[0][5]+REDp[1][5]+REDp[2][5]+REDp[3][5] + SB[5];
      float4 o;
      o.x = s0 + SB[6] + B0;
      o.y = s1 + SB[7] + B1;
      o.z = tanh_(s2 + SB[8] + B2);
      o.w = tanh_(s3 + SB[9] + B3);
      *(float4*)(y_out + (size_t)b * Sn * 4 + (size_t)s * 4) = o;
    }
    xp += 6;
  }
#undef GCH
}

extern "C" void kernel_launch(void* const* d_in, const int* in_sizes, int n_in,
                              void* d_out, int out_size, void* d_ws, size_t ws_size,
                              hipStream_t stream)
{
  const float* x        = (const float*)d_in[0];
  const float* w_ih     = (const float*)d_in[1];
  const float* w_hh     = (const float*)d_in[2];
  const float* b_ih     = (const float*)d_in[3];
  const float* b_hh     = (const float*)d_in[4];
  const float* w_gain   = (const float*)d_in[5];
  const float* b_gain   = (const float*)d_in[6];
  const float* w_bias   = (const float*)d_in[7];
  const float* b_bias   = (const float*)d_in[8];
  const float* w_reflex = (const float*)d_in[9];
  const float* b_reflex = (const float*)d_in[10];
  const float* w_policy = (const float*)d_in[11];
  const float* b_policy = (const float*)d_in[12];
  const float* w_motor  = (const float*)d_in[13];
  const float* b_motor  = (const float*)d_in[14];

  float* y_out  = (float*)d_out;
  float* router = (float*)d_out + (size_t)Bn * Sn * 4;

  bio_rnn<<<dim3(Bn), dim3(NT), 0, stream>>>(
      x, w_ih, w_hh, b_ih, b_hh, w_gain, b_gain, w_bias, b_bias,
      w_reflex, b_reflex, w_policy, b_policy, w_motor, b_motor,
      y_out, router);
}